// Round 1
// baseline (635.090 us; speedup 1.0000x reference)
//
#include <hip/hip_runtime.h>

#define T_STEPS 100
#define BATCH   256
#define IN_DIM  784
#define HID_DIM 1024
#define OUT_DIM 10
#define M_ROWS  (T_STEPS * BATCH)   // 25600
#define DECAY   0.6f
#define THRESH  0.9f

// ---------------------------------------------------------------------------
// GEMM1: C[M x H] = A[M x I] * W[I x H], fp32, row-major.
// 128x128 tile, BK=16, 256 threads, 8x8 per thread (4+4 split each dim).
// ---------------------------------------------------------------------------
#define BM 128
#define BN 128
#define BK 16
#define LDS_STRIDE 132   // +4 padding to break bank-conflict strides

__global__ __launch_bounds__(256) void gemm1_f32(const float* __restrict__ A,
                                                 const float* __restrict__ W,
                                                 float* __restrict__ C) {
    __shared__ float As[BK][LDS_STRIDE];   // transposed: As[k][m]
    __shared__ float Bs[BK][LDS_STRIDE];   // Bs[k][n]

    const int tid = threadIdx.x;
    const int n0  = blockIdx.x * BN;
    const int m0  = blockIdx.y * BM;

    const int tx = tid & 15;   // 0..15  -> column groups
    const int ty = tid >> 4;   // 0..15  -> row groups

    // A-tile load mapping: 128 rows x 16 k = 512 float4; thread t does f=t and f=t+256
    const int a_r  = tid >> 2;          // 0..63
    const int a_kv = (tid & 3) << 2;    // 0,4,8,12
    // B-tile load mapping: 16 rows x 128 n = 512 float4
    const int b_r  = tid >> 5;          // 0..7
    const int b_c  = (tid & 31) << 2;   // 0..124

    float acc[2][4][2][4];
    #pragma unroll
    for (int im = 0; im < 2; ++im)
        #pragma unroll
        for (int i = 0; i < 4; ++i)
            #pragma unroll
            for (int jn = 0; jn < 2; ++jn)
                #pragma unroll
                for (int j = 0; j < 4; ++j)
                    acc[im][i][jn][j] = 0.0f;

    for (int kt = 0; kt < IN_DIM; kt += BK) {
        // --- stage A (transposed into LDS) ---
        float4 a0 = *(const float4*)&A[(size_t)(m0 + a_r)      * IN_DIM + kt + a_kv];
        float4 a1 = *(const float4*)&A[(size_t)(m0 + 64 + a_r) * IN_DIM + kt + a_kv];
        // --- stage B ---
        float4 w0 = *(const float4*)&W[(size_t)(kt + b_r)     * HID_DIM + n0 + b_c];
        float4 w1 = *(const float4*)&W[(size_t)(kt + b_r + 8) * HID_DIM + n0 + b_c];

        As[a_kv + 0][a_r] = a0.x;  As[a_kv + 1][a_r] = a0.y;
        As[a_kv + 2][a_r] = a0.z;  As[a_kv + 3][a_r] = a0.w;
        As[a_kv + 0][64 + a_r] = a1.x;  As[a_kv + 1][64 + a_r] = a1.y;
        As[a_kv + 2][64 + a_r] = a1.z;  As[a_kv + 3][64 + a_r] = a1.w;
        *(float4*)&Bs[b_r][b_c]     = w0;
        *(float4*)&Bs[b_r + 8][b_c] = w1;

        __syncthreads();

        #pragma unroll
        for (int k = 0; k < BK; ++k) {
            float a[8], b[8];
            *(float4*)&a[0] = *(const float4*)&As[k][ty * 4];
            *(float4*)&a[4] = *(const float4*)&As[k][64 + ty * 4];
            *(float4*)&b[0] = *(const float4*)&Bs[k][tx * 4];
            *(float4*)&b[4] = *(const float4*)&Bs[k][64 + tx * 4];
            #pragma unroll
            for (int im = 0; im < 2; ++im)
                #pragma unroll
                for (int i = 0; i < 4; ++i)
                    #pragma unroll
                    for (int jn = 0; jn < 2; ++jn)
                        #pragma unroll
                        for (int j = 0; j < 4; ++j)
                            acc[im][i][jn][j] += a[im * 4 + i] * b[jn * 4 + j];
        }
        __syncthreads();
    }

    // epilogue: coalesced float4 stores
    #pragma unroll
    for (int im = 0; im < 2; ++im) {
        #pragma unroll
        for (int i = 0; i < 4; ++i) {
            const int m = m0 + im * 64 + ty * 4 + i;
            #pragma unroll
            for (int jn = 0; jn < 2; ++jn) {
                const int n = n0 + jn * 64 + tx * 4;
                float4 v = make_float4(acc[im][i][jn][0], acc[im][i][jn][1],
                                       acc[im][i][jn][2], acc[im][i][jn][3]);
                *(float4*)&C[(size_t)m * HID_DIM + n] = v;
            }
        }
    }
}

// ---------------------------------------------------------------------------
// LIF1: in-place over hidden region [T][B*H]; one thread per 4 neurons.
// ---------------------------------------------------------------------------
__global__ __launch_bounds__(256) void lif1(float* __restrict__ hid) {
    const int idx = blockIdx.x * blockDim.x + threadIdx.x;   // 0..65535
    float4* h4 = (float4*)hid;
    const int stride4 = (BATCH * HID_DIM) / 4;               // 65536
    float4 mem = make_float4(0.f, 0.f, 0.f, 0.f);
    for (int t = 0; t < T_STEPS; ++t) {
        float4 u = h4[t * stride4 + idx];
        float4 s;
        mem.x = mem.x * DECAY + u.x; s.x = (mem.x >= THRESH) ? 1.f : 0.f; mem.x -= s.x * THRESH;
        mem.y = mem.y * DECAY + u.y; s.y = (mem.y >= THRESH) ? 1.f : 0.f; mem.y -= s.y * THRESH;
        mem.z = mem.z * DECAY + u.z; s.z = (mem.z >= THRESH) ? 1.f : 0.f; mem.z -= s.z * THRESH;
        mem.w = mem.w * DECAY + u.w; s.w = (mem.w >= THRESH) ? 1.f : 0.f; mem.w -= s.w * THRESH;
        h4[t * stride4 + idx] = s;
    }
}

// ---------------------------------------------------------------------------
// GEMM2: out_u[M x O] = spikes[M x H] @ W2[H x O].  One wave per row.
// Spikes are almost entirely zero -> skip accumulation when s == 0.
// ---------------------------------------------------------------------------
__global__ __launch_bounds__(256) void gemm2(const float* __restrict__ S,
                                             const float* __restrict__ W2,
                                             float* __restrict__ outu) {
    const int gtid = blockIdx.x * blockDim.x + threadIdx.x;
    const int row  = gtid >> 6;
    const int lane = gtid & 63;
    if (row >= M_ROWS) return;

    const float* srow = S + (size_t)row * HID_DIM;
    float acc[OUT_DIM];
    #pragma unroll
    for (int o = 0; o < OUT_DIM; ++o) acc[o] = 0.f;

    for (int k = lane; k < HID_DIM; k += 64) {
        float s = srow[k];
        if (s != 0.f) {
            const float* w = W2 + (size_t)k * OUT_DIM;
            #pragma unroll
            for (int o = 0; o < OUT_DIM; ++o) acc[o] += s * w[o];
        }
    }
    #pragma unroll
    for (int o = 0; o < OUT_DIM; ++o) {
        float v = acc[o];
        #pragma unroll
        for (int off = 32; off > 0; off >>= 1) v += __shfl_down(v, off, 64);
        if (lane == 0) outu[(size_t)row * OUT_DIM + o] = v;
    }
}

// ---------------------------------------------------------------------------
// LIF2: in-place over output region [T][B*O]; one thread per neuron.
// ---------------------------------------------------------------------------
__global__ __launch_bounds__(256) void lif2(float* __restrict__ outp) {
    const int n = blockIdx.x * blockDim.x + threadIdx.x;
    const int stride = BATCH * OUT_DIM;   // 2560
    if (n >= stride) return;
    float mem = 0.f;
    for (int t = 0; t < T_STEPS; ++t) {
        float u = outp[t * stride + n];
        mem = mem * DECAY + u;
        float s = (mem >= THRESH) ? 1.f : 0.f;
        mem -= s * THRESH;
        outp[t * stride + n] = s;
    }
}

extern "C" void kernel_launch(void* const* d_in, const int* in_sizes, int n_in,
                              void* d_out, int out_size, void* d_ws, size_t ws_size,
                              hipStream_t stream) {
    const float* x  = (const float*)d_in[0];   // [T, B, I]
    const float* W1 = (const float*)d_in[1];   // [I, H]
    const float* W2 = (const float*)d_in[2];   // [H, O]
    float* out  = (float*)d_out;
    float* hid  = out;                                    // [T*B, H]
    float* outu = out + (size_t)M_ROWS * HID_DIM;         // [T*B, O]

    dim3 g1(HID_DIM / BN, M_ROWS / BM);                   // (8, 200)
    gemm1_f32<<<g1, 256, 0, stream>>>(x, W1, hid);

    lif1<<<(BATCH * HID_DIM / 4) / 256, 256, 0, stream>>>(hid);

    gemm2<<<(M_ROWS * 64) / 256, 256, 0, stream>>>(hid, W2, outu);

    lif2<<<(BATCH * OUT_DIM + 255) / 256, 256, 0, stream>>>(outu);
}

// Round 2
// 385.373 us; speedup vs baseline: 1.6480x; 1.6480x over previous
//
#include <hip/hip_runtime.h>
#include <hip/hip_bf16.h>

#define T_STEPS 100
#define BATCH   256
#define IN_DIM  784
#define HID_DIM 1024
#define OUT_DIM 10
#define M_ROWS  (T_STEPS * BATCH)   // 25600
#define KPAD    800                 // IN_DIM padded to multiple of 32
#define DECAY   0.6f
#define THRESH  0.9f

typedef __attribute__((ext_vector_type(8))) short bf16x8;
typedef __attribute__((ext_vector_type(4))) float f32x4;

// ---------------------------------------------------------------------------
// W1 transpose + hi/lo bf16 split:  W1[784][1024] fp32
//   -> Th[1024][800] bf16 (W_hi),  Tl[1024][800] bf16 (W - W_hi)
// x in {0,1} is exact in bf16, so x@W_hi + x@W_lo reproduces fp32 GEMM to
// ~1e-5 — far inside the spike-flip window.
// ---------------------------------------------------------------------------
__global__ __launch_bounds__(256) void w1_split_T(const float* __restrict__ W1,
                                                  unsigned short* __restrict__ Th,
                                                  unsigned short* __restrict__ Tl) {
    __shared__ unsigned short lh[32][33];
    __shared__ unsigned short ll[32][33];
    const int nb = blockIdx.x * 32;   // n tile
    const int kb = blockIdx.y * 32;   // k tile (0..768, covers KPAD=800 -> 25 tiles)
    const int t  = threadIdx.x;
    const int ln = t & 31, lk = t >> 5;   // load: col n, 8 k-rows per pass
    #pragma unroll
    for (int i = 0; i < 4; ++i) {
        const int k = kb + lk + i * 8;
        const float w = (k < IN_DIM) ? W1[(size_t)k * HID_DIM + nb + ln] : 0.f;
        __hip_bfloat16 h = __float2bfloat16(w);
        float hf = __bfloat162float(h);
        __hip_bfloat16 l = __float2bfloat16(w - hf);
        lh[lk + i * 8][ln] = __builtin_bit_cast(unsigned short, h);
        ll[lk + i * 8][ln] = __builtin_bit_cast(unsigned short, l);
    }
    __syncthreads();
    const int o_n = t >> 3;            // 0..31
    const int o_k = (t & 7) * 4;       // 0..28
    ushort4 vh, vl;
    vh.x = lh[o_k + 0][o_n]; vh.y = lh[o_k + 1][o_n];
    vh.z = lh[o_k + 2][o_n]; vh.w = lh[o_k + 3][o_n];
    vl.x = ll[o_k + 0][o_n]; vl.y = ll[o_k + 1][o_n];
    vl.z = ll[o_k + 2][o_n]; vl.w = ll[o_k + 3][o_n];
    *(ushort4*)&Th[(size_t)(nb + o_n) * KPAD + kb + o_k] = vh;
    *(ushort4*)&Tl[(size_t)(nb + o_n) * KPAD + kb + o_k] = vl;
}

// ---------------------------------------------------------------------------
// GEMM1 (MFMA): C[25600 x 1024] = X[25600 x 784] @ (Th + Tl)
// 128x128 tile, BK=32, 4 waves, each wave 64x64 = 4x4 tiles of 16x16x32.
// LDS rows padded to 40 bf16 (80 B) -> 2-way max on ds_read_b128 (free).
// ---------------------------------------------------------------------------
__global__ __launch_bounds__(256) void gemm1_mfma(const float* __restrict__ X,
                                                  const unsigned short* __restrict__ Th,
                                                  const unsigned short* __restrict__ Tl,
                                                  float* __restrict__ C) {
    __shared__ unsigned short As[128 * 40];
    __shared__ unsigned short Bh[128 * 40];
    __shared__ unsigned short Bl[128 * 40];

    const int tid  = threadIdx.x;
    const int m0   = blockIdx.y * 128;
    const int n0   = blockIdx.x * 128;
    const int lane = tid & 63, wv = tid >> 6;
    const int wm   = (wv & 1) * 64, wn = (wv >> 1) * 64;
    const int ml   = lane & 15, quad = lane >> 4;

    // A staging: 128 rows x 8 float4-chunks of k; 256 thr x 4 rows each
    const int a_r  = tid >> 3;      // 0..31 (+32,+64,+96)
    const int a_kq = tid & 7;       // float4 index in k (0..7)
    // B staging: 128 rows x 4 16B-chunks of k; 256 thr x 2 rows each
    const int b_n  = tid >> 2;      // 0..63 (+64)
    const int b_c  = tid & 3;       // 16B chunk (8 bf16)

    f32x4 acc[4][4];
    #pragma unroll
    for (int i = 0; i < 4; ++i)
        #pragma unroll
        for (int j = 0; j < 4; ++j)
            acc[i][j] = (f32x4){0.f, 0.f, 0.f, 0.f};

    for (int kt = 0; kt < KPAD; kt += 32) {
        // ---- stage A (fp32 -> bf16 truncation; exact for {0,1}) ----
        const bool av = (kt + a_kq * 4) < IN_DIM;
        #pragma unroll
        for (int i = 0; i < 4; ++i) {
            const int r = a_r + i * 32;
            float4 v = av ? *(const float4*)&X[(size_t)(m0 + r) * IN_DIM + kt + a_kq * 4]
                          : make_float4(0.f, 0.f, 0.f, 0.f);
            ushort4 u;
            u.x = (unsigned short)(__builtin_bit_cast(unsigned int, v.x) >> 16);
            u.y = (unsigned short)(__builtin_bit_cast(unsigned int, v.y) >> 16);
            u.z = (unsigned short)(__builtin_bit_cast(unsigned int, v.z) >> 16);
            u.w = (unsigned short)(__builtin_bit_cast(unsigned int, v.w) >> 16);
            *(ushort4*)&As[r * 40 + a_kq * 4] = u;
        }
        // ---- stage B (already bf16, pre-transposed [n][k]) ----
        #pragma unroll
        for (int i = 0; i < 2; ++i) {
            const int n = b_n + i * 64;
            const size_t g = (size_t)(n0 + n) * KPAD + kt + b_c * 8;
            float4 h = *(const float4*)&Th[g];
            float4 l = *(const float4*)&Tl[g];
            *(float4*)&Bh[n * 40 + b_c * 8] = h;
            *(float4*)&Bl[n * 40 + b_c * 8] = l;
        }
        __syncthreads();

        bf16x8 af[4], bhf[4], blf[4];
        #pragma unroll
        for (int i = 0; i < 4; ++i)
            af[i] = *(const bf16x8*)&As[(wm + i * 16 + ml) * 40 + quad * 8];
        #pragma unroll
        for (int j = 0; j < 4; ++j) {
            bhf[j] = *(const bf16x8*)&Bh[(wn + j * 16 + ml) * 40 + quad * 8];
            blf[j] = *(const bf16x8*)&Bl[(wn + j * 16 + ml) * 40 + quad * 8];
        }
        #pragma unroll
        for (int i = 0; i < 4; ++i)
            #pragma unroll
            for (int j = 0; j < 4; ++j) {
                acc[i][j] = __builtin_amdgcn_mfma_f32_16x16x32_bf16(af[i], bhf[j], acc[i][j], 0, 0, 0);
                acc[i][j] = __builtin_amdgcn_mfma_f32_16x16x32_bf16(af[i], blf[j], acc[i][j], 0, 0, 0);
            }
        __syncthreads();
    }

    // epilogue: C/D layout col=lane&15, row=quad*4+reg
    #pragma unroll
    for (int i = 0; i < 4; ++i)
        #pragma unroll
        for (int j = 0; j < 4; ++j) {
            const int row = m0 + wm + i * 16 + quad * 4;
            const int col = n0 + wn + j * 16 + ml;
            #pragma unroll
            for (int r = 0; r < 4; ++r)
                C[(size_t)(row + r) * HID_DIM + col] = acc[i][j][r];
        }
}

// ---------------------------------------------------------------------------
// LIF1: in-place over hidden region [T][B*H]; one thread per 4 neurons.
// ---------------------------------------------------------------------------
__global__ __launch_bounds__(256) void lif1(float* __restrict__ hid) {
    const int idx = blockIdx.x * blockDim.x + threadIdx.x;
    float4* h4 = (float4*)hid;
    const int stride4 = (BATCH * HID_DIM) / 4;
    float4 mem = make_float4(0.f, 0.f, 0.f, 0.f);
    for (int t = 0; t < T_STEPS; ++t) {
        float4 u = h4[t * stride4 + idx];
        float4 s;
        mem.x = mem.x * DECAY + u.x; s.x = (mem.x >= THRESH) ? 1.f : 0.f; mem.x -= s.x * THRESH;
        mem.y = mem.y * DECAY + u.y; s.y = (mem.y >= THRESH) ? 1.f : 0.f; mem.y -= s.y * THRESH;
        mem.z = mem.z * DECAY + u.z; s.z = (mem.z >= THRESH) ? 1.f : 0.f; mem.z -= s.z * THRESH;
        mem.w = mem.w * DECAY + u.w; s.w = (mem.w >= THRESH) ? 1.f : 0.f; mem.w -= s.w * THRESH;
        h4[t * stride4 + idx] = s;
    }
}

// ---------------------------------------------------------------------------
// GEMM2: out_u[M x O] = spikes[M x H] @ W2[H x O].  One wave per row;
// spikes are sparse -> skip zero terms.
// ---------------------------------------------------------------------------
__global__ __launch_bounds__(256) void gemm2(const float* __restrict__ S,
                                             const float* __restrict__ W2,
                                             float* __restrict__ outu) {
    const int gtid = blockIdx.x * blockDim.x + threadIdx.x;
    const int row  = gtid >> 6;
    const int lane = gtid & 63;
    if (row >= M_ROWS) return;

    const float* srow = S + (size_t)row * HID_DIM;
    float acc[OUT_DIM];
    #pragma unroll
    for (int o = 0; o < OUT_DIM; ++o) acc[o] = 0.f;

    for (int k = lane; k < HID_DIM; k += 64) {
        float s = srow[k];
        if (s != 0.f) {
            const float* w = W2 + (size_t)k * OUT_DIM;
            #pragma unroll
            for (int o = 0; o < OUT_DIM; ++o) acc[o] += s * w[o];
        }
    }
    #pragma unroll
    for (int o = 0; o < OUT_DIM; ++o) {
        float v = acc[o];
        #pragma unroll
        for (int off = 32; off > 0; off >>= 1) v += __shfl_down(v, off, 64);
        if (lane == 0) outu[(size_t)row * OUT_DIM + o] = v;
    }
}

// ---------------------------------------------------------------------------
// LIF2: in-place over output region [T][B*O]; one thread per neuron.
// ---------------------------------------------------------------------------
__global__ __launch_bounds__(256) void lif2(float* __restrict__ outp) {
    const int n = blockIdx.x * blockDim.x + threadIdx.x;
    const int stride = BATCH * OUT_DIM;
    if (n >= stride) return;
    float mem = 0.f;
    for (int t = 0; t < T_STEPS; ++t) {
        float u = outp[t * stride + n];
        mem = mem * DECAY + u;
        float s = (mem >= THRESH) ? 1.f : 0.f;
        mem -= s * THRESH;
        outp[t * stride + n] = s;
    }
}

extern "C" void kernel_launch(void* const* d_in, const int* in_sizes, int n_in,
                              void* d_out, int out_size, void* d_ws, size_t ws_size,
                              hipStream_t stream) {
    const float* x  = (const float*)d_in[0];   // [T, B, I]
    const float* W1 = (const float*)d_in[1];   // [I, H]
    const float* W2 = (const float*)d_in[2];   // [H, O]
    float* out  = (float*)d_out;
    float* hid  = out;                                    // [T*B, H]
    float* outu = out + (size_t)M_ROWS * HID_DIM;         // [T*B, O]

    // ws: Th [1024][800] bf16, Tl [1024][800] bf16  (3.28 MB total)
    unsigned short* Th = (unsigned short*)d_ws;
    unsigned short* Tl = Th + (size_t)HID_DIM * KPAD;

    dim3 gt(HID_DIM / 32, KPAD / 32);                     // (32, 25)
    w1_split_T<<<gt, 256, 0, stream>>>(W1, Th, Tl);

    dim3 g1(HID_DIM / 128, M_ROWS / 128);                 // (8, 200)
    gemm1_mfma<<<g1, 256, 0, stream>>>(x, Th, Tl, hid);

    lif1<<<(BATCH * HID_DIM / 4) / 256, 256, 0, stream>>>(hid);

    gemm2<<<(M_ROWS * 64) / 256, 256, 0, stream>>>(hid, W2, outu);

    lif2<<<(BATCH * OUT_DIM + 255) / 256, 256, 0, stream>>>(outu);
}